// Round 15
// baseline (124.722 us; speedup 1.0000x reference)
//
#include <hip/hip_runtime.h>

// GCN 2-layer: out = A_hat @ relu(A_hat @ (X W1) + b1) W2 + b2
// A_hat = D^-1/2 (A + I) D^-1/2.
//
// R15: R14 base (122.4us) + deeper gather pipeline in agg1 (4-deep level
// before the 2-deep/scalar tails; per-eg edge count ~Poisson(4) so the
// 4-deep level fires for ~57% of lane groups) and self-loop row load
// hoisted above the edge loop in both aggs (1 extra load in flight).
// Everything else identical to R14.

#define CIN 256
#define CHID 128
#define COUT 64
#define NSCAT 256

typedef unsigned short ushort_t;
typedef unsigned int uint_t;
typedef __attribute__((ext_vector_type(8))) short short8;   // 8 bf16 (4 VGPR)
typedef __attribute__((ext_vector_type(4))) float f32x4;    // MFMA acc

__device__ inline ushort_t f2bf(float f) {  // RNE
  union { float f; uint_t u; } v; v.f = f;
  uint_t r = v.u + 0x7FFFu + ((v.u >> 16) & 1u);
  return (ushort_t)(r >> 16);
}
__device__ inline float bf_lo(uint_t u) {
  union { uint_t u; float f; } v; v.u = u << 16;
  return v.f;
}
__device__ inline float bf_hi(uint_t u) {
  union { uint_t u; float f; } v; v.u = u & 0xFFFF0000u;
  return v.f;
}
__device__ inline uint_t pack2(float a, float b) {
  return (uint_t)f2bf(a) | ((uint_t)f2bf(b) << 16);
}
__device__ inline void acc8(float* a, uint4 u) {
  a[0] += bf_lo(u.x); a[1] += bf_hi(u.x);
  a[2] += bf_lo(u.y); a[3] += bf_hi(u.y);
  a[4] += bf_lo(u.z); a[5] += bf_hi(u.z);
  a[6] += bf_lo(u.w); a[7] += bf_hi(u.w);
}

// ---------- pass 1 (merged): per-block LDS histogram + weight transpose ----
__global__ __launch_bounds__(256) void k_pre(const int* __restrict__ dst,
                                             int* __restrict__ cntmat,
                                             const float* __restrict__ W1,
                                             const float* __restrict__ W2,
                                             ushort_t* __restrict__ Wt1,
                                             ushort_t* __restrict__ Wt2,
                                             int e, int nbk) {
  const int tid = threadIdx.x;
  if (blockIdx.x < NSCAT) {
    __shared__ int h[256];
    h[tid] = 0;
    __syncthreads();
    const int per = (e + NSCAT - 1) / NSCAT;
    const int lo = blockIdx.x * per;
    const int hi = min(e, lo + per);
    for (int i = lo + tid; i < hi; i += 256) atomicAdd(&h[dst[i] >> 8], 1);
    __syncthreads();
    if (tid < nbk) cntmat[blockIdx.x * nbk + tid] = h[tid];
  } else {
    int i = (blockIdx.x - NSCAT) * 256 + tid;
    if (i < CIN * CHID) {
      int k = i % CIN, c = i / CIN;
      Wt1[i] = f2bf(W1[(size_t)k * CHID + c]);
    } else {
      int j = i - CIN * CHID;
      if (j < CHID * COUT) {
        int k = j % CHID, c = j / CHID;
        Wt2[j] = f2bf(W2[(size_t)k * COUT + c]);
      }
    }
  }
}

// ---------- pass 2: exclusive scan of cntmat[:,k] per bucket column ----------
__global__ __launch_bounds__(256) void k_colscan(int* __restrict__ cntmat,
                                                 int* __restrict__ btot, int nbk) {
  __shared__ int s[NSCAT];
  const int k = blockIdx.x;
  const int tid = threadIdx.x;
  const int v = cntmat[tid * nbk + k];
  s[tid] = v;
  __syncthreads();
  for (int off = 1; off < NSCAT; off <<= 1) {
    int t = (tid >= off) ? s[tid - off] : 0;
    __syncthreads();
    s[tid] += t;
    __syncthreads();
  }
  cntmat[tid * nbk + k] = s[tid] - v;  // exclusive within column
  if (tid == NSCAT - 1) btot[k] = s[tid];
}

// ---------- pass 3: scatter packed (src<<8 | dst&255) to bucket regions ----
__global__ __launch_bounds__(256) void k_bscatter(const int* __restrict__ src,
                                                  const int* __restrict__ dst,
                                                  const int* __restrict__ cntmat,
                                                  const int* __restrict__ btot,
                                                  int* __restrict__ pairs,
                                                  int e, int nbk) {
  __shared__ int s[256];
  __shared__ int cur[256];
  const int tid = threadIdx.x;
  const int v = (tid < nbk) ? btot[tid] : 0;
  s[tid] = v;
  __syncthreads();
  for (int off = 1; off < 256; off <<= 1) {
    int t = (tid >= off) ? s[tid - off] : 0;
    __syncthreads();
    s[tid] += t;
    __syncthreads();
  }
  cur[tid] = (tid < nbk) ? (s[tid] - v + cntmat[blockIdx.x * nbk + tid]) : 0;
  __syncthreads();
  const int per = (e + NSCAT - 1) / NSCAT;
  const int lo = blockIdx.x * per;
  const int hi = min(e, lo + per);
  for (int i = lo + tid; i < hi; i += 256) {
    int d = dst[i];
    int off = atomicAdd(&cur[d >> 8], 1);
    pairs[off] = (src[i] << 8) | (d & 255);
  }
}

// ---------- pass 4: per-bucket CSR + rowptr + dinv ----------
__global__ __launch_bounds__(256) void k_bbuild(const int* __restrict__ pairs,
                                                const int* __restrict__ btot,
                                                int* __restrict__ rowptr,
                                                float* __restrict__ dinv,
                                                ushort_t* __restrict__ csr,
                                                int n, int e, int nbk) {
  __shared__ int h[256];
  __shared__ int s[256];
  __shared__ int sbnd[2];
  const int tid = threadIdx.x;
  const int b = blockIdx.x;
  {
    const int v = (tid < nbk) ? btot[tid] : 0;
    s[tid] = v;
    __syncthreads();
    for (int off = 1; off < 256; off <<= 1) {
      int t = (tid >= off) ? s[tid - off] : 0;
      __syncthreads();
      s[tid] += t;
      __syncthreads();
    }
    if (tid == b) {
      sbnd[0] = s[tid] - v;
      sbnd[1] = s[tid];
    }
    __syncthreads();
  }
  const int lo = sbnd[0];
  const int hi = sbnd[1];
  h[tid] = 0;
  __syncthreads();
  for (int i = lo + tid; i < hi; i += 256) atomicAdd(&h[pairs[i] & 255], 1);
  __syncthreads();
  const int deg = h[tid];
  s[tid] = deg;
  __syncthreads();
  for (int off = 1; off < 256; off <<= 1) {
    int t = (tid >= off) ? s[tid - off] : 0;
    __syncthreads();
    s[tid] += t;
    __syncthreads();
  }
  const int excl = s[tid] - deg;
  const int node = (b << 8) + tid;
  if (node < n) {
    rowptr[node] = lo + excl;
    dinv[node] = rsqrtf((float)(deg + 1));  // +1 self-loop
  }
  if (b == 0 && tid == 0) rowptr[n] = e;
  h[tid] = lo + excl;  // reuse as cursor
  __syncthreads();
  for (int i = lo + tid; i < hi; i += 256) {
    int p = pairs[i];
    int slot = atomicAdd(&h[p & 255], 1);
    csr[slot] = (ushort_t)(((uint_t)p) >> 8);
  }
}

// ---------- MFMA GEMM: BM=128, BK=32, 4 waves, coalesced A staging (R12) ----
template <int K, int BN, bool XBF16>
__global__ __launch_bounds__(256) void k_gemm_mfma(
    const void* __restrict__ Xv, const ushort_t* __restrict__ Wt,
    const float* __restrict__ dinv, ushort_t* __restrict__ out, int M) {
  constexpr int BM = 128, BK = 32;
  constexpr int NSUB = BN / 16;
  constexpr int ASZ = BM * BK;
  constexpr int BSZ = BK * BN;
  constexpr int NCH = K / BK;
  constexpr int AITF = ASZ / 4 / 256;  // 4 float4 iters (fp32 X)
  constexpr int AITB = ASZ / 8 / 256;  // 2 uint4 iters (bf16 X)
  constexpr int BIT = BSZ / 8 / 256;   // 2 / 1

  __shared__ ushort_t As[2][ASZ];
  __shared__ ushort_t Bs[2][BSZ];

  const int tid = threadIdx.x;
  const int lane = tid & 63;
  const int w = tid >> 6;
  const int row0 = blockIdx.x * BM;

  const float* Xf = (const float*)Xv;
  const ushort_t* Xb = (const ushort_t*)Xv;

  float4 arf[AITF];
  uint4 arb[AITB];
  uint4 brg[BIT];

  auto load_A = [&](int kc) {
    if constexpr (XBF16) {
#pragma unroll
      for (int i = 0; i < AITB; ++i) {
        int fi = i * 256 + tid;
        int r = fi >> 2, q = fi & 3;
        int gr = min(row0 + r, M - 1);
        arb[i] = *(const uint4*)(Xb + (size_t)gr * K + kc + q * 8);
      }
    } else {
#pragma unroll
      for (int i = 0; i < AITF; ++i) {
        int fi = i * 256 + tid;
        int r = fi >> 3, q = fi & 7;
        int gr = min(row0 + r, M - 1);
        arf[i] = *(const float4*)(Xf + (size_t)gr * K + kc + q * 4);
      }
    }
#pragma unroll
    for (int i = 0; i < BIT; ++i) {
      int g = i * 256 + tid;
      int nf = g >> 6, l = g & 63;
      int c = nf * 16 + (l & 15), k0 = (l >> 4) * 8;
      brg[i] = *(const uint4*)(Wt + (size_t)c * K + kc + k0);
    }
  };

  auto write_lds = [&](int buf) {
    if constexpr (XBF16) {
#pragma unroll
      for (int i = 0; i < AITB; ++i) {
        int fi = i * 256 + tid;
        int r = fi >> 2, q = fi & 3;
        int flat = (r >> 4) * 512 + ((r & 15) + 16 * q) * 8;
        *(uint4*)&As[buf][flat] = arb[i];
      }
    } else {
#pragma unroll
      for (int i = 0; i < AITF; ++i) {
        int fi = i * 256 + tid;
        int r = fi >> 3, q = fi & 7;
        int kb = q >> 1, ko = (q & 1) * 4;
        int flat = (r >> 4) * 512 + ((r & 15) + 16 * kb) * 8 + ko;
        uint2 p;
        p.x = pack2(arf[i].x, arf[i].y);
        p.y = pack2(arf[i].z, arf[i].w);
        *(uint2*)&As[buf][flat] = p;
      }
    }
#pragma unroll
    for (int i = 0; i < BIT; ++i) {
      int g = i * 256 + tid;
      int nf = g >> 6, l = g & 63;
      *(uint4*)&Bs[buf][nf * 512 + l * 8] = brg[i];
    }
  };

  f32x4 acc[2][NSUB];
#pragma unroll
  for (int mi = 0; mi < 2; ++mi)
#pragma unroll
    for (int ni = 0; ni < NSUB; ++ni)
      acc[mi][ni] = (f32x4){0.f, 0.f, 0.f, 0.f};

  load_A(0);
  write_lds(0);

#pragma unroll 1
  for (int ch = 0; ch < NCH; ++ch) {
    const int cur = ch & 1;
    __syncthreads();
    if (ch + 1 < NCH) load_A((ch + 1) * BK);

    short8 af[2];
#pragma unroll
    for (int mi = 0; mi < 2; ++mi)
      af[mi] = *(const short8*)&As[cur][(2 * w + mi) * 512 + lane * 8];
    short8 bf[NSUB];
#pragma unroll
    for (int ni = 0; ni < NSUB; ++ni)
      bf[ni] = *(const short8*)&Bs[cur][ni * 512 + lane * 8];

#pragma unroll
    for (int mi = 0; mi < 2; ++mi)
#pragma unroll
      for (int ni = 0; ni < NSUB; ++ni)
        acc[mi][ni] = __builtin_amdgcn_mfma_f32_16x16x32_bf16(
            af[mi], bf[ni], acc[mi][ni], 0, 0, 0);

    if (ch + 1 < NCH) write_lds(cur ^ 1);
  }

  const int qrow = (lane >> 4) * 4;
  const int col16 = lane & 15;
#pragma unroll
  for (int mi = 0; mi < 2; ++mi) {
    int rbase = row0 + w * 32 + mi * 16 + qrow;
#pragma unroll
    for (int v = 0; v < 4; ++v) {
      int row = rbase + v;
      if (row < M) {
        float dn = dinv[row];
#pragma unroll
        for (int ni = 0; ni < NSUB; ++ni)
          out[(size_t)row * BN + ni * 16 + col16] = f2bf(dn * acc[mi][ni][v]);
      }
    }
  }
}

// ---------- agg1: C=128, wave-per-node, 4/2/1-deep gather pipeline ----------
__global__ __launch_bounds__(256) void k_aggw_h(
    const ushort_t* __restrict__ hh, const int* __restrict__ rowptr,
    const ushort_t* __restrict__ csr, const float* __restrict__ dinv,
    const float* __restrict__ bias, ushort_t* __restrict__ out, int n) {
  const int tid = threadIdx.x;
  const int node = blockIdx.x * 4 + (tid >> 6);
  if (node >= n) return;
  const int lane = tid & 63;
  const int q = lane & 15;
  const int eg = lane >> 4;

  // self-loop row load issued before the edge loop (one more in flight;
  // all 4 egs hit the same cache line)
  const uint4 uself = *(const uint4*)&hh[(size_t)node * CHID + q * 8];

  float a0[8], a1[8], a2[8], a3[8];
#pragma unroll
  for (int j = 0; j < 8; ++j) { a0[j] = 0.f; a1[j] = 0.f; a2[j] = 0.f; a3[j] = 0.f; }

  const int beg = rowptr[node];
  const int end = rowptr[node + 1];
  int k = beg + eg;
  // 4-deep: four independent gathers in flight
  for (; k + 12 < end; k += 16) {
    int s0 = csr[k], s1 = csr[k + 4], s2 = csr[k + 8], s3 = csr[k + 12];
    uint4 u0 = *(const uint4*)&hh[(size_t)s0 * CHID + q * 8];
    uint4 u1 = *(const uint4*)&hh[(size_t)s1 * CHID + q * 8];
    uint4 u2 = *(const uint4*)&hh[(size_t)s2 * CHID + q * 8];
    uint4 u3 = *(const uint4*)&hh[(size_t)s3 * CHID + q * 8];
    acc8(a0, u0); acc8(a1, u1); acc8(a2, u2); acc8(a3, u3);
  }
  // 2-deep tail
  for (; k + 4 < end; k += 8) {
    int s0 = csr[k], s1 = csr[k + 4];
    uint4 u0 = *(const uint4*)&hh[(size_t)s0 * CHID + q * 8];
    uint4 u1 = *(const uint4*)&hh[(size_t)s1 * CHID + q * 8];
    acc8(a0, u0); acc8(a1, u1);
  }
  if (k < end) {
    int s0 = csr[k];
    uint4 u0 = *(const uint4*)&hh[(size_t)s0 * CHID + q * 8];
    acc8(a0, u0);
  }
#pragma unroll
  for (int j = 0; j < 8; ++j) a0[j] += (a1[j] + a2[j]) + a3[j];
#pragma unroll
  for (int j = 0; j < 8; ++j) {
    a0[j] += __shfl_xor(a0[j], 16);
    a0[j] += __shfl_xor(a0[j], 32);
  }
  if (eg == 0) {
    acc8(a0, uself);  // self-loop
    const float dn = dinv[node];
    float4 b0 = *(const float4*)&bias[q * 8];
    float4 b1 = *(const float4*)&bias[q * 8 + 4];
    float r[8];
    r[0] = dn * a0[0] + b0.x; r[1] = dn * a0[1] + b0.y;
    r[2] = dn * a0[2] + b0.z; r[3] = dn * a0[3] + b0.w;
    r[4] = dn * a0[4] + b1.x; r[5] = dn * a0[5] + b1.y;
    r[6] = dn * a0[6] + b1.z; r[7] = dn * a0[7] + b1.w;
#pragma unroll
    for (int j = 0; j < 8; ++j) r[j] = fmaxf(r[j], 0.0f);
    uint4 o;
    o.x = pack2(r[0], r[1]); o.y = pack2(r[2], r[3]);
    o.z = pack2(r[4], r[5]); o.w = pack2(r[6], r[7]);
    *(uint4*)&out[(size_t)node * CHID + q * 8] = o;
  }
}

// ---------- agg2: C=64, wave-per-node, 2/1-deep gather, fp32 out ----------
__global__ __launch_bounds__(256) void k_aggw_o(
    const ushort_t* __restrict__ hh, const int* __restrict__ rowptr,
    const ushort_t* __restrict__ csr, const float* __restrict__ dinv,
    const float* __restrict__ bias, float* __restrict__ out, int n) {
  const int tid = threadIdx.x;
  const int node = blockIdx.x * 4 + (tid >> 6);
  if (node >= n) return;
  const int lane = tid & 63;
  const int q = lane & 7;
  const int eg = lane >> 3;

  const uint4 uself = *(const uint4*)&hh[(size_t)node * COUT + q * 8];

  float a0[8], a1[8];
#pragma unroll
  for (int j = 0; j < 8; ++j) { a0[j] = 0.f; a1[j] = 0.f; }

  const int beg = rowptr[node];
  const int end = rowptr[node + 1];
  int k = beg + eg;
  for (; k + 8 < end; k += 16) {
    int s0 = csr[k], s1 = csr[k + 8];
    uint4 u0 = *(const uint4*)&hh[(size_t)s0 * COUT + q * 8];
    uint4 u1 = *(const uint4*)&hh[(size_t)s1 * COUT + q * 8];
    acc8(a0, u0); acc8(a1, u1);
  }
  if (k < end) {
    int s0 = csr[k];
    uint4 u0 = *(const uint4*)&hh[(size_t)s0 * COUT + q * 8];
    acc8(a0, u0);
  }
#pragma unroll
  for (int j = 0; j < 8; ++j) a0[j] += a1[j];
#pragma unroll
  for (int j = 0; j < 8; ++j) {
    a0[j] += __shfl_xor(a0[j], 8);
    a0[j] += __shfl_xor(a0[j], 16);
    a0[j] += __shfl_xor(a0[j], 32);
  }
  if (eg == 0) {
    acc8(a0, uself);  // self-loop
    const float dn = dinv[node];
    float4 b0 = *(const float4*)&bias[q * 8];
    float4 b1 = *(const float4*)&bias[q * 8 + 4];
    float4 o0, o1;
    o0.x = dn * a0[0] + b0.x; o0.y = dn * a0[1] + b0.y;
    o0.z = dn * a0[2] + b0.z; o0.w = dn * a0[3] + b0.w;
    o1.x = dn * a0[4] + b1.x; o1.y = dn * a0[5] + b1.y;
    o1.z = dn * a0[6] + b1.z; o1.w = dn * a0[7] + b1.w;
    *(float4*)&out[(size_t)node * COUT + q * 8] = o0;
    *(float4*)&out[(size_t)node * COUT + q * 8 + 4] = o1;
  }
}

extern "C" void kernel_launch(void* const* d_in, const int* in_sizes, int n_in,
                              void* d_out, int out_size, void* d_ws, size_t ws_size,
                              hipStream_t stream) {
  const float* x  = (const float*)d_in[0];
  const int*   ei = (const int*)d_in[1];
  const float* W1 = (const float*)d_in[2];
  const float* b1 = (const float*)d_in[3];
  const float* W2 = (const float*)d_in[4];
  const float* b2 = (const float*)d_in[5];
  float* out = (float*)d_out;

  const int n = in_sizes[0] / CIN;  // 50000
  const int e = in_sizes[1] / 2;    // 800000
  const int* src = ei;
  const int* dst = ei + e;
  const int nbk = (n + 255) >> 8;   // buckets (196)

  // workspace layout (aligned 256B)
  size_t off = 0;
  auto alloc = [&](size_t bytes) {
    size_t o = off;
    off = (off + bytes + 255) & ~(size_t)255;
    return o;
  };
  char* ws = (char*)d_ws;
  int*      cntmat = (int*)(ws + alloc((size_t)NSCAT * 256 * 4));
  int*      btot   = (int*)(ws + alloc(256 * 4));
  int*      rowptr = (int*)(ws + alloc((size_t)(n + 1) * 4));
  float*    dinv   = (float*)(ws + alloc((size_t)n * 4));
  ushort_t* csr    = (ushort_t*)(ws + alloc((size_t)e * 2));
  int*      pairs  = (int*)(ws + alloc((size_t)e * 4));
  ushort_t* wt1    = (ushort_t*)(ws + alloc((size_t)CIN * CHID * 2));
  ushort_t* wt2    = (ushort_t*)(ws + alloc((size_t)CHID * COUT * 2));
  ushort_t* hhA    = (ushort_t*)(ws + alloc((size_t)n * CHID * 2));
  ushort_t* hhB    = (ushort_t*)(ws + alloc((size_t)n * CHID * 2));

  const int WTB = (CIN * CHID + CHID * COUT + 255) / 256;  // 160

  // --- hist + weight transpose (1 dispatch) ---
  k_pre<<<NSCAT + WTB, 256, 0, stream>>>(dst, cntmat, W1, W2, wt1, wt2, e, nbk);
  // --- offsets (parallel) ---
  k_colscan<<<nbk, NSCAT, 0, stream>>>(cntmat, btot, nbk);
  // --- scatter packed pairs ---
  k_bscatter<<<NSCAT, 256, 0, stream>>>(src, dst, cntmat, btot, pairs, e, nbk);
  // --- per-bucket CSR + rowptr + dinv ---
  k_bbuild<<<nbk, 256, 0, stream>>>(pairs, btot, rowptr, dinv, csr, n, e, nbk);

  // --- layer 1 ---
  k_gemm_mfma<CIN, CHID, false><<<(n + 127) / 128, 256, 0, stream>>>(
      x, wt1, dinv, hhA, n);
  k_aggw_h<<<(n + 3) / 4, 256, 0, stream>>>(hhA, rowptr, csr, dinv, b1, hhB, n);

  // --- layer 2 ---
  k_gemm_mfma<CHID, COUT, true><<<(n + 127) / 128, 256, 0, stream>>>(
      hhB, wt2, dinv, hhA, n);
  k_aggw_o<<<(n + 3) / 4, 256, 0, stream>>>(hhA, rowptr, csr, dinv, b2, out, n);
}

// Round 16
// 118.440 us; speedup vs baseline: 1.0530x; 1.0530x over previous
//
#include <hip/hip_runtime.h>

// GCN 2-layer: out = A_hat @ relu(A_hat @ (X W1) + b1) W2 + b2
// A_hat = D^-1/2 (A + I) D^-1/2.
//
// R16: R14 base (122.4us best; R15's 4-deep agg + self-loop hoist regressed
// and is reverted) + ONE change: int4-vectorized edge-stream reads in k_pre
// (hist) and k_bscatter (4 edges per load instruction; partition defined on
// int4 granularity consistently in both so cntmat matches).

#define CIN 256
#define CHID 128
#define COUT 64
#define NSCAT 256

typedef unsigned short ushort_t;
typedef unsigned int uint_t;
typedef __attribute__((ext_vector_type(8))) short short8;   // 8 bf16 (4 VGPR)
typedef __attribute__((ext_vector_type(4))) float f32x4;    // MFMA acc

__device__ inline ushort_t f2bf(float f) {  // RNE
  union { float f; uint_t u; } v; v.f = f;
  uint_t r = v.u + 0x7FFFu + ((v.u >> 16) & 1u);
  return (ushort_t)(r >> 16);
}
__device__ inline float bf_lo(uint_t u) {
  union { uint_t u; float f; } v; v.u = u << 16;
  return v.f;
}
__device__ inline float bf_hi(uint_t u) {
  union { uint_t u; float f; } v; v.u = u & 0xFFFF0000u;
  return v.f;
}
__device__ inline uint_t pack2(float a, float b) {
  return (uint_t)f2bf(a) | ((uint_t)f2bf(b) << 16);
}
__device__ inline void acc8(float* a, uint4 u) {
  a[0] += bf_lo(u.x); a[1] += bf_hi(u.x);
  a[2] += bf_lo(u.y); a[3] += bf_hi(u.y);
  a[4] += bf_lo(u.z); a[5] += bf_hi(u.z);
  a[6] += bf_lo(u.w); a[7] += bf_hi(u.w);
}

// edge-range partition on int4 granularity (shared by k_pre and k_bscatter)
__device__ inline void edge_range4(int e, int blk, int& lo4, int& hi4) {
  int n4 = (e + 3) >> 2;
  int per4 = (n4 + NSCAT - 1) / NSCAT;
  lo4 = blk * per4;
  hi4 = min(n4, lo4 + per4);
}

// ---------- pass 1 (merged): per-block LDS histogram + weight transpose ----
__global__ __launch_bounds__(256) void k_pre(const int* __restrict__ dst,
                                             int* __restrict__ cntmat,
                                             const float* __restrict__ W1,
                                             const float* __restrict__ W2,
                                             ushort_t* __restrict__ Wt1,
                                             ushort_t* __restrict__ Wt2,
                                             int e, int nbk) {
  const int tid = threadIdx.x;
  if (blockIdx.x < NSCAT) {
    __shared__ int h[256];
    h[tid] = 0;
    __syncthreads();
    int lo4, hi4;
    edge_range4(e, blockIdx.x, lo4, hi4);
    for (int i4 = lo4 + tid; i4 < hi4; i4 += 256) {
      int i = i4 * 4;
      if (i + 3 < e) {
        int4 d4 = *(const int4*)(dst + i);
        atomicAdd(&h[d4.x >> 8], 1);
        atomicAdd(&h[d4.y >> 8], 1);
        atomicAdd(&h[d4.z >> 8], 1);
        atomicAdd(&h[d4.w >> 8], 1);
      } else {
        for (int j = i; j < e; ++j) atomicAdd(&h[dst[j] >> 8], 1);
      }
    }
    __syncthreads();
    if (tid < nbk) cntmat[blockIdx.x * nbk + tid] = h[tid];
  } else {
    int i = (blockIdx.x - NSCAT) * 256 + tid;
    if (i < CIN * CHID) {
      int k = i % CIN, c = i / CIN;
      Wt1[i] = f2bf(W1[(size_t)k * CHID + c]);
    } else {
      int j = i - CIN * CHID;
      if (j < CHID * COUT) {
        int k = j % CHID, c = j / CHID;
        Wt2[j] = f2bf(W2[(size_t)k * COUT + c]);
      }
    }
  }
}

// ---------- pass 2: exclusive scan of cntmat[:,k] per bucket column ----------
__global__ __launch_bounds__(256) void k_colscan(int* __restrict__ cntmat,
                                                 int* __restrict__ btot, int nbk) {
  __shared__ int s[NSCAT];
  const int k = blockIdx.x;
  const int tid = threadIdx.x;
  const int v = cntmat[tid * nbk + k];
  s[tid] = v;
  __syncthreads();
  for (int off = 1; off < NSCAT; off <<= 1) {
    int t = (tid >= off) ? s[tid - off] : 0;
    __syncthreads();
    s[tid] += t;
    __syncthreads();
  }
  cntmat[tid * nbk + k] = s[tid] - v;  // exclusive within column
  if (tid == NSCAT - 1) btot[k] = s[tid];
}

// ---------- pass 3: scatter packed (src<<8 | dst&255) to bucket regions ----
__global__ __launch_bounds__(256) void k_bscatter(const int* __restrict__ src,
                                                  const int* __restrict__ dst,
                                                  const int* __restrict__ cntmat,
                                                  const int* __restrict__ btot,
                                                  int* __restrict__ pairs,
                                                  int e, int nbk) {
  __shared__ int s[256];
  __shared__ int cur[256];
  const int tid = threadIdx.x;
  const int v = (tid < nbk) ? btot[tid] : 0;
  s[tid] = v;
  __syncthreads();
  for (int off = 1; off < 256; off <<= 1) {
    int t = (tid >= off) ? s[tid - off] : 0;
    __syncthreads();
    s[tid] += t;
    __syncthreads();
  }
  cur[tid] = (tid < nbk) ? (s[tid] - v + cntmat[blockIdx.x * nbk + tid]) : 0;
  __syncthreads();
  int lo4, hi4;
  edge_range4(e, blockIdx.x, lo4, hi4);
  for (int i4 = lo4 + tid; i4 < hi4; i4 += 256) {
    int i = i4 * 4;
    if (i + 3 < e) {
      int4 s4 = *(const int4*)(src + i);
      int4 d4 = *(const int4*)(dst + i);
      int o0 = atomicAdd(&cur[d4.x >> 8], 1);
      pairs[o0] = (s4.x << 8) | (d4.x & 255);
      int o1 = atomicAdd(&cur[d4.y >> 8], 1);
      pairs[o1] = (s4.y << 8) | (d4.y & 255);
      int o2 = atomicAdd(&cur[d4.z >> 8], 1);
      pairs[o2] = (s4.z << 8) | (d4.z & 255);
      int o3 = atomicAdd(&cur[d4.w >> 8], 1);
      pairs[o3] = (s4.w << 8) | (d4.w & 255);
    } else {
      for (int j = i; j < e; ++j) {
        int d = dst[j];
        int off = atomicAdd(&cur[d >> 8], 1);
        pairs[off] = (src[j] << 8) | (d & 255);
      }
    }
  }
}

// ---------- pass 4: per-bucket CSR + rowptr + dinv ----------
__global__ __launch_bounds__(256) void k_bbuild(const int* __restrict__ pairs,
                                                const int* __restrict__ btot,
                                                int* __restrict__ rowptr,
                                                float* __restrict__ dinv,
                                                ushort_t* __restrict__ csr,
                                                int n, int e, int nbk) {
  __shared__ int h[256];
  __shared__ int s[256];
  __shared__ int sbnd[2];
  const int tid = threadIdx.x;
  const int b = blockIdx.x;
  {
    const int v = (tid < nbk) ? btot[tid] : 0;
    s[tid] = v;
    __syncthreads();
    for (int off = 1; off < 256; off <<= 1) {
      int t = (tid >= off) ? s[tid - off] : 0;
      __syncthreads();
      s[tid] += t;
      __syncthreads();
    }
    if (tid == b) {
      sbnd[0] = s[tid] - v;
      sbnd[1] = s[tid];
    }
    __syncthreads();
  }
  const int lo = sbnd[0];
  const int hi = sbnd[1];
  h[tid] = 0;
  __syncthreads();
  for (int i = lo + tid; i < hi; i += 256) atomicAdd(&h[pairs[i] & 255], 1);
  __syncthreads();
  const int deg = h[tid];
  s[tid] = deg;
  __syncthreads();
  for (int off = 1; off < 256; off <<= 1) {
    int t = (tid >= off) ? s[tid - off] : 0;
    __syncthreads();
    s[tid] += t;
    __syncthreads();
  }
  const int excl = s[tid] - deg;
  const int node = (b << 8) + tid;
  if (node < n) {
    rowptr[node] = lo + excl;
    dinv[node] = rsqrtf((float)(deg + 1));  // +1 self-loop
  }
  if (b == 0 && tid == 0) rowptr[n] = e;
  h[tid] = lo + excl;  // reuse as cursor
  __syncthreads();
  for (int i = lo + tid; i < hi; i += 256) {
    int p = pairs[i];
    int slot = atomicAdd(&h[p & 255], 1);
    csr[slot] = (ushort_t)(((uint_t)p) >> 8);
  }
}

// ---------- MFMA GEMM: BM=128, BK=32, 4 waves, coalesced A staging (R12) ----
template <int K, int BN, bool XBF16>
__global__ __launch_bounds__(256) void k_gemm_mfma(
    const void* __restrict__ Xv, const ushort_t* __restrict__ Wt,
    const float* __restrict__ dinv, ushort_t* __restrict__ out, int M) {
  constexpr int BM = 128, BK = 32;
  constexpr int NSUB = BN / 16;
  constexpr int ASZ = BM * BK;
  constexpr int BSZ = BK * BN;
  constexpr int NCH = K / BK;
  constexpr int AITF = ASZ / 4 / 256;  // 4 float4 iters (fp32 X)
  constexpr int AITB = ASZ / 8 / 256;  // 2 uint4 iters (bf16 X)
  constexpr int BIT = BSZ / 8 / 256;   // 2 / 1

  __shared__ ushort_t As[2][ASZ];
  __shared__ ushort_t Bs[2][BSZ];

  const int tid = threadIdx.x;
  const int lane = tid & 63;
  const int w = tid >> 6;
  const int row0 = blockIdx.x * BM;

  const float* Xf = (const float*)Xv;
  const ushort_t* Xb = (const ushort_t*)Xv;

  float4 arf[AITF];
  uint4 arb[AITB];
  uint4 brg[BIT];

  auto load_A = [&](int kc) {
    if constexpr (XBF16) {
#pragma unroll
      for (int i = 0; i < AITB; ++i) {
        int fi = i * 256 + tid;
        int r = fi >> 2, q = fi & 3;
        int gr = min(row0 + r, M - 1);
        arb[i] = *(const uint4*)(Xb + (size_t)gr * K + kc + q * 8);
      }
    } else {
#pragma unroll
      for (int i = 0; i < AITF; ++i) {
        int fi = i * 256 + tid;
        int r = fi >> 3, q = fi & 7;
        int gr = min(row0 + r, M - 1);
        arf[i] = *(const float4*)(Xf + (size_t)gr * K + kc + q * 4);
      }
    }
#pragma unroll
    for (int i = 0; i < BIT; ++i) {
      int g = i * 256 + tid;
      int nf = g >> 6, l = g & 63;
      int c = nf * 16 + (l & 15), k0 = (l >> 4) * 8;
      brg[i] = *(const uint4*)(Wt + (size_t)c * K + kc + k0);
    }
  };

  auto write_lds = [&](int buf) {
    if constexpr (XBF16) {
#pragma unroll
      for (int i = 0; i < AITB; ++i) {
        int fi = i * 256 + tid;
        int r = fi >> 2, q = fi & 3;
        int flat = (r >> 4) * 512 + ((r & 15) + 16 * q) * 8;
        *(uint4*)&As[buf][flat] = arb[i];
      }
    } else {
#pragma unroll
      for (int i = 0; i < AITF; ++i) {
        int fi = i * 256 + tid;
        int r = fi >> 3, q = fi & 7;
        int kb = q >> 1, ko = (q & 1) * 4;
        int flat = (r >> 4) * 512 + ((r & 15) + 16 * kb) * 8 + ko;
        uint2 p;
        p.x = pack2(arf[i].x, arf[i].y);
        p.y = pack2(arf[i].z, arf[i].w);
        *(uint2*)&As[buf][flat] = p;
      }
    }
#pragma unroll
    for (int i = 0; i < BIT; ++i) {
      int g = i * 256 + tid;
      int nf = g >> 6, l = g & 63;
      *(uint4*)&Bs[buf][nf * 512 + l * 8] = brg[i];
    }
  };

  f32x4 acc[2][NSUB];
#pragma unroll
  for (int mi = 0; mi < 2; ++mi)
#pragma unroll
    for (int ni = 0; ni < NSUB; ++ni)
      acc[mi][ni] = (f32x4){0.f, 0.f, 0.f, 0.f};

  load_A(0);
  write_lds(0);

#pragma unroll 1
  for (int ch = 0; ch < NCH; ++ch) {
    const int cur = ch & 1;
    __syncthreads();
    if (ch + 1 < NCH) load_A((ch + 1) * BK);

    short8 af[2];
#pragma unroll
    for (int mi = 0; mi < 2; ++mi)
      af[mi] = *(const short8*)&As[cur][(2 * w + mi) * 512 + lane * 8];
    short8 bf[NSUB];
#pragma unroll
    for (int ni = 0; ni < NSUB; ++ni)
      bf[ni] = *(const short8*)&Bs[cur][ni * 512 + lane * 8];

#pragma unroll
    for (int mi = 0; mi < 2; ++mi)
#pragma unroll
      for (int ni = 0; ni < NSUB; ++ni)
        acc[mi][ni] = __builtin_amdgcn_mfma_f32_16x16x32_bf16(
            af[mi], bf[ni], acc[mi][ni], 0, 0, 0);

    if (ch + 1 < NCH) write_lds(cur ^ 1);
  }

  const int qrow = (lane >> 4) * 4;
  const int col16 = lane & 15;
#pragma unroll
  for (int mi = 0; mi < 2; ++mi) {
    int rbase = row0 + w * 32 + mi * 16 + qrow;
#pragma unroll
    for (int v = 0; v < 4; ++v) {
      int row = rbase + v;
      if (row < M) {
        float dn = dinv[row];
#pragma unroll
        for (int ni = 0; ni < NSUB; ++ni)
          out[(size_t)row * BN + ni * 16 + col16] = f2bf(dn * acc[mi][ni][v]);
      }
    }
  }
}

// ---------- agg1: C=128, wave-per-node, x2-unrolled gather (R14) ----------
__global__ __launch_bounds__(256) void k_aggw_h(
    const ushort_t* __restrict__ hh, const int* __restrict__ rowptr,
    const ushort_t* __restrict__ csr, const float* __restrict__ dinv,
    const float* __restrict__ bias, ushort_t* __restrict__ out, int n) {
  const int tid = threadIdx.x;
  const int node = blockIdx.x * 4 + (tid >> 6);
  if (node >= n) return;
  const int lane = tid & 63;
  const int q = lane & 15;
  const int eg = lane >> 4;

  float acc[8], acc2[8];
#pragma unroll
  for (int j = 0; j < 8; ++j) { acc[j] = 0.0f; acc2[j] = 0.0f; }

  const int beg = rowptr[node];
  const int end = rowptr[node + 1];
  int k = beg + eg;
  for (; k + 4 < end; k += 8) {
    int s0 = csr[k];
    int s1 = csr[k + 4];
    uint4 u0 = *(const uint4*)&hh[(size_t)s0 * CHID + q * 8];
    uint4 u1 = *(const uint4*)&hh[(size_t)s1 * CHID + q * 8];
    acc8(acc, u0);
    acc8(acc2, u1);
  }
  if (k < end) {
    int s0 = csr[k];
    uint4 u0 = *(const uint4*)&hh[(size_t)s0 * CHID + q * 8];
    acc8(acc, u0);
  }
#pragma unroll
  for (int j = 0; j < 8; ++j) acc[j] += acc2[j];
#pragma unroll
  for (int j = 0; j < 8; ++j) {
    acc[j] += __shfl_xor(acc[j], 16);
    acc[j] += __shfl_xor(acc[j], 32);
  }
  if (eg == 0) {
    uint4 u = *(const uint4*)&hh[(size_t)node * CHID + q * 8];  // self-loop
    acc8(acc, u);
    const float dn = dinv[node];
    float4 b0 = *(const float4*)&bias[q * 8];
    float4 b1 = *(const float4*)&bias[q * 8 + 4];
    float r[8];
    r[0] = dn * acc[0] + b0.x; r[1] = dn * acc[1] + b0.y;
    r[2] = dn * acc[2] + b0.z; r[3] = dn * acc[3] + b0.w;
    r[4] = dn * acc[4] + b1.x; r[5] = dn * acc[5] + b1.y;
    r[6] = dn * acc[6] + b1.z; r[7] = dn * acc[7] + b1.w;
#pragma unroll
    for (int j = 0; j < 8; ++j) r[j] = fmaxf(r[j], 0.0f);
    uint4 o;
    o.x = pack2(r[0], r[1]); o.y = pack2(r[2], r[3]);
    o.z = pack2(r[4], r[5]); o.w = pack2(r[6], r[7]);
    *(uint4*)&out[(size_t)node * CHID + q * 8] = o;
  }
}

// ---------- agg2: C=64, wave-per-node, x2-unrolled gather (R14) ----------
__global__ __launch_bounds__(256) void k_aggw_o(
    const ushort_t* __restrict__ hh, const int* __restrict__ rowptr,
    const ushort_t* __restrict__ csr, const float* __restrict__ dinv,
    const float* __restrict__ bias, float* __restrict__ out, int n) {
  const int tid = threadIdx.x;
  const int node = blockIdx.x * 4 + (tid >> 6);
  if (node >= n) return;
  const int lane = tid & 63;
  const int q = lane & 7;
  const int eg = lane >> 3;

  float acc[8], acc2[8];
#pragma unroll
  for (int j = 0; j < 8; ++j) { acc[j] = 0.0f; acc2[j] = 0.0f; }

  const int beg = rowptr[node];
  const int end = rowptr[node + 1];
  int k = beg + eg;
  for (; k + 8 < end; k += 16) {
    int s0 = csr[k];
    int s1 = csr[k + 8];
    uint4 u0 = *(const uint4*)&hh[(size_t)s0 * COUT + q * 8];
    uint4 u1 = *(const uint4*)&hh[(size_t)s1 * COUT + q * 8];
    acc8(acc, u0);
    acc8(acc2, u1);
  }
  if (k < end) {
    int s0 = csr[k];
    uint4 u0 = *(const uint4*)&hh[(size_t)s0 * COUT + q * 8];
    acc8(acc, u0);
  }
#pragma unroll
  for (int j = 0; j < 8; ++j) acc[j] += acc2[j];
#pragma unroll
  for (int j = 0; j < 8; ++j) {
    acc[j] += __shfl_xor(acc[j], 8);
    acc[j] += __shfl_xor(acc[j], 16);
    acc[j] += __shfl_xor(acc[j], 32);
  }
  if (eg == 0) {
    uint4 u = *(const uint4*)&hh[(size_t)node * COUT + q * 8];  // self-loop
    acc8(acc, u);
    const float dn = dinv[node];
    float4 b0 = *(const float4*)&bias[q * 8];
    float4 b1 = *(const float4*)&bias[q * 8 + 4];
    float4 o0, o1;
    o0.x = dn * acc[0] + b0.x; o0.y = dn * acc[1] + b0.y;
    o0.z = dn * acc[2] + b0.z; o0.w = dn * acc[3] + b0.w;
    o1.x = dn * acc[4] + b1.x; o1.y = dn * acc[5] + b1.y;
    o1.z = dn * acc[6] + b1.z; o1.w = dn * acc[7] + b1.w;
    *(float4*)&out[(size_t)node * COUT + q * 8] = o0;
    *(float4*)&out[(size_t)node * COUT + q * 8 + 4] = o1;
  }
}

extern "C" void kernel_launch(void* const* d_in, const int* in_sizes, int n_in,
                              void* d_out, int out_size, void* d_ws, size_t ws_size,
                              hipStream_t stream) {
  const float* x  = (const float*)d_in[0];
  const int*   ei = (const int*)d_in[1];
  const float* W1 = (const float*)d_in[2];
  const float* b1 = (const float*)d_in[3];
  const float* W2 = (const float*)d_in[4];
  const float* b2 = (const float*)d_in[5];
  float* out = (float*)d_out;

  const int n = in_sizes[0] / CIN;  // 50000
  const int e = in_sizes[1] / 2;    // 800000
  const int* src = ei;
  const int* dst = ei + e;
  const int nbk = (n + 255) >> 8;   // buckets (196)

  // workspace layout (aligned 256B)
  size_t off = 0;
  auto alloc = [&](size_t bytes) {
    size_t o = off;
    off = (off + bytes + 255) & ~(size_t)255;
    return o;
  };
  char* ws = (char*)d_ws;
  int*      cntmat = (int*)(ws + alloc((size_t)NSCAT * 256 * 4));
  int*      btot   = (int*)(ws + alloc(256 * 4));
  int*      rowptr = (int*)(ws + alloc((size_t)(n + 1) * 4));
  float*    dinv   = (float*)(ws + alloc((size_t)n * 4));
  ushort_t* csr    = (ushort_t*)(ws + alloc((size_t)e * 2));
  int*      pairs  = (int*)(ws + alloc((size_t)e * 4));
  ushort_t* wt1    = (ushort_t*)(ws + alloc((size_t)CIN * CHID * 2));
  ushort_t* wt2    = (ushort_t*)(ws + alloc((size_t)CHID * COUT * 2));
  ushort_t* hhA    = (ushort_t*)(ws + alloc((size_t)n * CHID * 2));
  ushort_t* hhB    = (ushort_t*)(ws + alloc((size_t)n * CHID * 2));

  const int WTB = (CIN * CHID + CHID * COUT + 255) / 256;  // 160

  // --- hist + weight transpose (1 dispatch) ---
  k_pre<<<NSCAT + WTB, 256, 0, stream>>>(dst, cntmat, W1, W2, wt1, wt2, e, nbk);
  // --- offsets (parallel) ---
  k_colscan<<<nbk, NSCAT, 0, stream>>>(cntmat, btot, nbk);
  // --- scatter packed pairs ---
  k_bscatter<<<NSCAT, 256, 0, stream>>>(src, dst, cntmat, btot, pairs, e, nbk);
  // --- per-bucket CSR + rowptr + dinv ---
  k_bbuild<<<nbk, 256, 0, stream>>>(pairs, btot, rowptr, dinv, csr, n, e, nbk);

  // --- layer 1 ---
  k_gemm_mfma<CIN, CHID, false><<<(n + 127) / 128, 256, 0, stream>>>(
      x, wt1, dinv, hhA, n);
  k_aggw_h<<<(n + 3) / 4, 256, 0, stream>>>(hhA, rowptr, csr, dinv, b1, hhB, n);

  // --- layer 2 ---
  k_gemm_mfma<CHID, COUT, true><<<(n + 127) / 128, 256, 0, stream>>>(
      hhB, wt2, dinv, hhA, n);
  k_aggw_o<<<(n + 3) / 4, 256, 0, stream>>>(hhA, rowptr, csr, dinv, b2, out, n);
}

// Round 17
// 115.363 us; speedup vs baseline: 1.0811x; 1.0267x over previous
//
#include <hip/hip_runtime.h>

// GCN 2-layer: out = A_hat @ relu(A_hat @ (X W1) + b1) W2 + b2
// A_hat = D^-1/2 (A + I) D^-1/2.
//
// R17: R16 base (118.4us) + ONE change: int4-vectorized pairs reads in
// k_bbuild (both the histogram pass and the scatter pass read the bucket's
// [lo,hi) range via aligned int4 loads with per-element guards; boundary
// overreads stay inside d_ws and are guarded out). 4x fewer load
// instructions on the 2x 6.4MB pairs traffic. Everything else identical.

#define CIN 256
#define CHID 128
#define COUT 64
#define NSCAT 256

typedef unsigned short ushort_t;
typedef unsigned int uint_t;
typedef __attribute__((ext_vector_type(8))) short short8;   // 8 bf16 (4 VGPR)
typedef __attribute__((ext_vector_type(4))) float f32x4;    // MFMA acc

__device__ inline ushort_t f2bf(float f) {  // RNE
  union { float f; uint_t u; } v; v.f = f;
  uint_t r = v.u + 0x7FFFu + ((v.u >> 16) & 1u);
  return (ushort_t)(r >> 16);
}
__device__ inline float bf_lo(uint_t u) {
  union { uint_t u; float f; } v; v.u = u << 16;
  return v.f;
}
__device__ inline float bf_hi(uint_t u) {
  union { uint_t u; float f; } v; v.u = u & 0xFFFF0000u;
  return v.f;
}
__device__ inline uint_t pack2(float a, float b) {
  return (uint_t)f2bf(a) | ((uint_t)f2bf(b) << 16);
}
__device__ inline void acc8(float* a, uint4 u) {
  a[0] += bf_lo(u.x); a[1] += bf_hi(u.x);
  a[2] += bf_lo(u.y); a[3] += bf_hi(u.y);
  a[4] += bf_lo(u.z); a[5] += bf_hi(u.z);
  a[6] += bf_lo(u.w); a[7] += bf_hi(u.w);
}

// edge-range partition on int4 granularity (shared by k_pre and k_bscatter)
__device__ inline void edge_range4(int e, int blk, int& lo4, int& hi4) {
  int n4 = (e + 3) >> 2;
  int per4 = (n4 + NSCAT - 1) / NSCAT;
  lo4 = blk * per4;
  hi4 = min(n4, lo4 + per4);
}

// ---------- pass 1 (merged): per-block LDS histogram + weight transpose ----
__global__ __launch_bounds__(256) void k_pre(const int* __restrict__ dst,
                                             int* __restrict__ cntmat,
                                             const float* __restrict__ W1,
                                             const float* __restrict__ W2,
                                             ushort_t* __restrict__ Wt1,
                                             ushort_t* __restrict__ Wt2,
                                             int e, int nbk) {
  const int tid = threadIdx.x;
  if (blockIdx.x < NSCAT) {
    __shared__ int h[256];
    h[tid] = 0;
    __syncthreads();
    int lo4, hi4;
    edge_range4(e, blockIdx.x, lo4, hi4);
    for (int i4 = lo4 + tid; i4 < hi4; i4 += 256) {
      int i = i4 * 4;
      if (i + 3 < e) {
        int4 d4 = *(const int4*)(dst + i);
        atomicAdd(&h[d4.x >> 8], 1);
        atomicAdd(&h[d4.y >> 8], 1);
        atomicAdd(&h[d4.z >> 8], 1);
        atomicAdd(&h[d4.w >> 8], 1);
      } else {
        for (int j = i; j < e; ++j) atomicAdd(&h[dst[j] >> 8], 1);
      }
    }
    __syncthreads();
    if (tid < nbk) cntmat[blockIdx.x * nbk + tid] = h[tid];
  } else {
    int i = (blockIdx.x - NSCAT) * 256 + tid;
    if (i < CIN * CHID) {
      int k = i % CIN, c = i / CIN;
      Wt1[i] = f2bf(W1[(size_t)k * CHID + c]);
    } else {
      int j = i - CIN * CHID;
      if (j < CHID * COUT) {
        int k = j % CHID, c = j / CHID;
        Wt2[j] = f2bf(W2[(size_t)k * COUT + c]);
      }
    }
  }
}

// ---------- pass 2: exclusive scan of cntmat[:,k] per bucket column ----------
__global__ __launch_bounds__(256) void k_colscan(int* __restrict__ cntmat,
                                                 int* __restrict__ btot, int nbk) {
  __shared__ int s[NSCAT];
  const int k = blockIdx.x;
  const int tid = threadIdx.x;
  const int v = cntmat[tid * nbk + k];
  s[tid] = v;
  __syncthreads();
  for (int off = 1; off < NSCAT; off <<= 1) {
    int t = (tid >= off) ? s[tid - off] : 0;
    __syncthreads();
    s[tid] += t;
    __syncthreads();
  }
  cntmat[tid * nbk + k] = s[tid] - v;  // exclusive within column
  if (tid == NSCAT - 1) btot[k] = s[tid];
}

// ---------- pass 3: scatter packed (src<<8 | dst&255) to bucket regions ----
__global__ __launch_bounds__(256) void k_bscatter(const int* __restrict__ src,
                                                  const int* __restrict__ dst,
                                                  const int* __restrict__ cntmat,
                                                  const int* __restrict__ btot,
                                                  int* __restrict__ pairs,
                                                  int e, int nbk) {
  __shared__ int s[256];
  __shared__ int cur[256];
  const int tid = threadIdx.x;
  const int v = (tid < nbk) ? btot[tid] : 0;
  s[tid] = v;
  __syncthreads();
  for (int off = 1; off < 256; off <<= 1) {
    int t = (tid >= off) ? s[tid - off] : 0;
    __syncthreads();
    s[tid] += t;
    __syncthreads();
  }
  cur[tid] = (tid < nbk) ? (s[tid] - v + cntmat[blockIdx.x * nbk + tid]) : 0;
  __syncthreads();
  int lo4, hi4;
  edge_range4(e, blockIdx.x, lo4, hi4);
  for (int i4 = lo4 + tid; i4 < hi4; i4 += 256) {
    int i = i4 * 4;
    if (i + 3 < e) {
      int4 s4 = *(const int4*)(src + i);
      int4 d4 = *(const int4*)(dst + i);
      int o0 = atomicAdd(&cur[d4.x >> 8], 1);
      pairs[o0] = (s4.x << 8) | (d4.x & 255);
      int o1 = atomicAdd(&cur[d4.y >> 8], 1);
      pairs[o1] = (s4.y << 8) | (d4.y & 255);
      int o2 = atomicAdd(&cur[d4.z >> 8], 1);
      pairs[o2] = (s4.z << 8) | (d4.z & 255);
      int o3 = atomicAdd(&cur[d4.w >> 8], 1);
      pairs[o3] = (s4.w << 8) | (d4.w & 255);
    } else {
      for (int j = i; j < e; ++j) {
        int d = dst[j];
        int off = atomicAdd(&cur[d >> 8], 1);
        pairs[off] = (src[j] << 8) | (d & 255);
      }
    }
  }
}

// ---------- pass 4: per-bucket CSR + rowptr + dinv (int4 pairs reads) ------
__global__ __launch_bounds__(256) void k_bbuild(const int* __restrict__ pairs,
                                                const int* __restrict__ btot,
                                                int* __restrict__ rowptr,
                                                float* __restrict__ dinv,
                                                ushort_t* __restrict__ csr,
                                                int n, int e, int nbk) {
  __shared__ int h[256];
  __shared__ int s[256];
  __shared__ int sbnd[2];
  const int tid = threadIdx.x;
  const int b = blockIdx.x;
  {
    const int v = (tid < nbk) ? btot[tid] : 0;
    s[tid] = v;
    __syncthreads();
    for (int off = 1; off < 256; off <<= 1) {
      int t = (tid >= off) ? s[tid - off] : 0;
      __syncthreads();
      s[tid] += t;
      __syncthreads();
    }
    if (tid == b) {
      sbnd[0] = s[tid] - v;
      sbnd[1] = s[tid];
    }
    __syncthreads();
  }
  const int lo = sbnd[0];
  const int hi = sbnd[1];
  const int i4lo = lo >> 2;
  const int i4hi = (hi + 3) >> 2;  // aligned cover; overreads stay in d_ws
  h[tid] = 0;
  __syncthreads();
  // histogram pass (int4)
  for (int i4 = i4lo + tid; i4 < i4hi; i4 += 256) {
    int i = i4 * 4;
    int4 p4 = *(const int4*)(pairs + i);
    if (i >= lo && i + 3 < hi) {
      atomicAdd(&h[p4.x & 255], 1);
      atomicAdd(&h[p4.y & 255], 1);
      atomicAdd(&h[p4.z & 255], 1);
      atomicAdd(&h[p4.w & 255], 1);
    } else {
      if (i + 0 >= lo && i + 0 < hi) atomicAdd(&h[p4.x & 255], 1);
      if (i + 1 >= lo && i + 1 < hi) atomicAdd(&h[p4.y & 255], 1);
      if (i + 2 >= lo && i + 2 < hi) atomicAdd(&h[p4.z & 255], 1);
      if (i + 3 >= lo && i + 3 < hi) atomicAdd(&h[p4.w & 255], 1);
    }
  }
  __syncthreads();
  const int deg = h[tid];
  s[tid] = deg;
  __syncthreads();
  for (int off = 1; off < 256; off <<= 1) {
    int t = (tid >= off) ? s[tid - off] : 0;
    __syncthreads();
    s[tid] += t;
    __syncthreads();
  }
  const int excl = s[tid] - deg;
  const int node = (b << 8) + tid;
  if (node < n) {
    rowptr[node] = lo + excl;
    dinv[node] = rsqrtf((float)(deg + 1));  // +1 self-loop
  }
  if (b == 0 && tid == 0) rowptr[n] = e;
  h[tid] = lo + excl;  // reuse as cursor
  __syncthreads();
  // scatter pass (int4)
  for (int i4 = i4lo + tid; i4 < i4hi; i4 += 256) {
    int i = i4 * 4;
    int4 p4 = *(const int4*)(pairs + i);
    if (i >= lo && i + 3 < hi) {
      int s0 = atomicAdd(&h[p4.x & 255], 1);
      csr[s0] = (ushort_t)(((uint_t)p4.x) >> 8);
      int s1 = atomicAdd(&h[p4.y & 255], 1);
      csr[s1] = (ushort_t)(((uint_t)p4.y) >> 8);
      int s2 = atomicAdd(&h[p4.z & 255], 1);
      csr[s2] = (ushort_t)(((uint_t)p4.z) >> 8);
      int s3 = atomicAdd(&h[p4.w & 255], 1);
      csr[s3] = (ushort_t)(((uint_t)p4.w) >> 8);
    } else {
      if (i + 0 >= lo && i + 0 < hi) {
        int s0 = atomicAdd(&h[p4.x & 255], 1);
        csr[s0] = (ushort_t)(((uint_t)p4.x) >> 8);
      }
      if (i + 1 >= lo && i + 1 < hi) {
        int s1 = atomicAdd(&h[p4.y & 255], 1);
        csr[s1] = (ushort_t)(((uint_t)p4.y) >> 8);
      }
      if (i + 2 >= lo && i + 2 < hi) {
        int s2 = atomicAdd(&h[p4.z & 255], 1);
        csr[s2] = (ushort_t)(((uint_t)p4.z) >> 8);
      }
      if (i + 3 >= lo && i + 3 < hi) {
        int s3 = atomicAdd(&h[p4.w & 255], 1);
        csr[s3] = (ushort_t)(((uint_t)p4.w) >> 8);
      }
    }
  }
}

// ---------- MFMA GEMM: BM=128, BK=32, 4 waves, coalesced A staging (R12) ----
template <int K, int BN, bool XBF16>
__global__ __launch_bounds__(256) void k_gemm_mfma(
    const void* __restrict__ Xv, const ushort_t* __restrict__ Wt,
    const float* __restrict__ dinv, ushort_t* __restrict__ out, int M) {
  constexpr int BM = 128, BK = 32;
  constexpr int NSUB = BN / 16;
  constexpr int ASZ = BM * BK;
  constexpr int BSZ = BK * BN;
  constexpr int NCH = K / BK;
  constexpr int AITF = ASZ / 4 / 256;  // 4 float4 iters (fp32 X)
  constexpr int AITB = ASZ / 8 / 256;  // 2 uint4 iters (bf16 X)
  constexpr int BIT = BSZ / 8 / 256;   // 2 / 1

  __shared__ ushort_t As[2][ASZ];
  __shared__ ushort_t Bs[2][BSZ];

  const int tid = threadIdx.x;
  const int lane = tid & 63;
  const int w = tid >> 6;
  const int row0 = blockIdx.x * BM;

  const float* Xf = (const float*)Xv;
  const ushort_t* Xb = (const ushort_t*)Xv;

  float4 arf[AITF];
  uint4 arb[AITB];
  uint4 brg[BIT];

  auto load_A = [&](int kc) {
    if constexpr (XBF16) {
#pragma unroll
      for (int i = 0; i < AITB; ++i) {
        int fi = i * 256 + tid;
        int r = fi >> 2, q = fi & 3;
        int gr = min(row0 + r, M - 1);
        arb[i] = *(const uint4*)(Xb + (size_t)gr * K + kc + q * 8);
      }
    } else {
#pragma unroll
      for (int i = 0; i < AITF; ++i) {
        int fi = i * 256 + tid;
        int r = fi >> 3, q = fi & 7;
        int gr = min(row0 + r, M - 1);
        arf[i] = *(const float4*)(Xf + (size_t)gr * K + kc + q * 4);
      }
    }
#pragma unroll
    for (int i = 0; i < BIT; ++i) {
      int g = i * 256 + tid;
      int nf = g >> 6, l = g & 63;
      int c = nf * 16 + (l & 15), k0 = (l >> 4) * 8;
      brg[i] = *(const uint4*)(Wt + (size_t)c * K + kc + k0);
    }
  };

  auto write_lds = [&](int buf) {
    if constexpr (XBF16) {
#pragma unroll
      for (int i = 0; i < AITB; ++i) {
        int fi = i * 256 + tid;
        int r = fi >> 2, q = fi & 3;
        int flat = (r >> 4) * 512 + ((r & 15) + 16 * q) * 8;
        *(uint4*)&As[buf][flat] = arb[i];
      }
    } else {
#pragma unroll
      for (int i = 0; i < AITF; ++i) {
        int fi = i * 256 + tid;
        int r = fi >> 3, q = fi & 7;
        int kb = q >> 1, ko = (q & 1) * 4;
        int flat = (r >> 4) * 512 + ((r & 15) + 16 * kb) * 8 + ko;
        uint2 p;
        p.x = pack2(arf[i].x, arf[i].y);
        p.y = pack2(arf[i].z, arf[i].w);
        *(uint2*)&As[buf][flat] = p;
      }
    }
#pragma unroll
    for (int i = 0; i < BIT; ++i) {
      int g = i * 256 + tid;
      int nf = g >> 6, l = g & 63;
      *(uint4*)&Bs[buf][nf * 512 + l * 8] = brg[i];
    }
  };

  f32x4 acc[2][NSUB];
#pragma unroll
  for (int mi = 0; mi < 2; ++mi)
#pragma unroll
    for (int ni = 0; ni < NSUB; ++ni)
      acc[mi][ni] = (f32x4){0.f, 0.f, 0.f, 0.f};

  load_A(0);
  write_lds(0);

#pragma unroll 1
  for (int ch = 0; ch < NCH; ++ch) {
    const int cur = ch & 1;
    __syncthreads();
    if (ch + 1 < NCH) load_A((ch + 1) * BK);

    short8 af[2];
#pragma unroll
    for (int mi = 0; mi < 2; ++mi)
      af[mi] = *(const short8*)&As[cur][(2 * w + mi) * 512 + lane * 8];
    short8 bf[NSUB];
#pragma unroll
    for (int ni = 0; ni < NSUB; ++ni)
      bf[ni] = *(const short8*)&Bs[cur][ni * 512 + lane * 8];

#pragma unroll
    for (int mi = 0; mi < 2; ++mi)
#pragma unroll
      for (int ni = 0; ni < NSUB; ++ni)
        acc[mi][ni] = __builtin_amdgcn_mfma_f32_16x16x32_bf16(
            af[mi], bf[ni], acc[mi][ni], 0, 0, 0);

    if (ch + 1 < NCH) write_lds(cur ^ 1);
  }

  const int qrow = (lane >> 4) * 4;
  const int col16 = lane & 15;
#pragma unroll
  for (int mi = 0; mi < 2; ++mi) {
    int rbase = row0 + w * 32 + mi * 16 + qrow;
#pragma unroll
    for (int v = 0; v < 4; ++v) {
      int row = rbase + v;
      if (row < M) {
        float dn = dinv[row];
#pragma unroll
        for (int ni = 0; ni < NSUB; ++ni)
          out[(size_t)row * BN + ni * 16 + col16] = f2bf(dn * acc[mi][ni][v]);
      }
    }
  }
}

// ---------- agg1: C=128, wave-per-node, x2-unrolled gather (R14) ----------
__global__ __launch_bounds__(256) void k_aggw_h(
    const ushort_t* __restrict__ hh, const int* __restrict__ rowptr,
    const ushort_t* __restrict__ csr, const float* __restrict__ dinv,
    const float* __restrict__ bias, ushort_t* __restrict__ out, int n) {
  const int tid = threadIdx.x;
  const int node = blockIdx.x * 4 + (tid >> 6);
  if (node >= n) return;
  const int lane = tid & 63;
  const int q = lane & 15;
  const int eg = lane >> 4;

  float acc[8], acc2[8];
#pragma unroll
  for (int j = 0; j < 8; ++j) { acc[j] = 0.0f; acc2[j] = 0.0f; }

  const int beg = rowptr[node];
  const int end = rowptr[node + 1];
  int k = beg + eg;
  for (; k + 4 < end; k += 8) {
    int s0 = csr[k];
    int s1 = csr[k + 4];
    uint4 u0 = *(const uint4*)&hh[(size_t)s0 * CHID + q * 8];
    uint4 u1 = *(const uint4*)&hh[(size_t)s1 * CHID + q * 8];
    acc8(acc, u0);
    acc8(acc2, u1);
  }
  if (k < end) {
    int s0 = csr[k];
    uint4 u0 = *(const uint4*)&hh[(size_t)s0 * CHID + q * 8];
    acc8(acc, u0);
  }
#pragma unroll
  for (int j = 0; j < 8; ++j) acc[j] += acc2[j];
#pragma unroll
  for (int j = 0; j < 8; ++j) {
    acc[j] += __shfl_xor(acc[j], 16);
    acc[j] += __shfl_xor(acc[j], 32);
  }
  if (eg == 0) {
    uint4 u = *(const uint4*)&hh[(size_t)node * CHID + q * 8];  // self-loop
    acc8(acc, u);
    const float dn = dinv[node];
    float4 b0 = *(const float4*)&bias[q * 8];
    float4 b1 = *(const float4*)&bias[q * 8 + 4];
    float r[8];
    r[0] = dn * acc[0] + b0.x; r[1] = dn * acc[1] + b0.y;
    r[2] = dn * acc[2] + b0.z; r[3] = dn * acc[3] + b0.w;
    r[4] = dn * acc[4] + b1.x; r[5] = dn * acc[5] + b1.y;
    r[6] = dn * acc[6] + b1.z; r[7] = dn * acc[7] + b1.w;
#pragma unroll
    for (int j = 0; j < 8; ++j) r[j] = fmaxf(r[j], 0.0f);
    uint4 o;
    o.x = pack2(r[0], r[1]); o.y = pack2(r[2], r[3]);
    o.z = pack2(r[4], r[5]); o.w = pack2(r[6], r[7]);
    *(uint4*)&out[(size_t)node * CHID + q * 8] = o;
  }
}

// ---------- agg2: C=64, wave-per-node, x2-unrolled gather (R14) ----------
__global__ __launch_bounds__(256) void k_aggw_o(
    const ushort_t* __restrict__ hh, const int* __restrict__ rowptr,
    const ushort_t* __restrict__ csr, const float* __restrict__ dinv,
    const float* __restrict__ bias, float* __restrict__ out, int n) {
  const int tid = threadIdx.x;
  const int node = blockIdx.x * 4 + (tid >> 6);
  if (node >= n) return;
  const int lane = tid & 63;
  const int q = lane & 7;
  const int eg = lane >> 3;

  float acc[8], acc2[8];
#pragma unroll
  for (int j = 0; j < 8; ++j) { acc[j] = 0.0f; acc2[j] = 0.0f; }

  const int beg = rowptr[node];
  const int end = rowptr[node + 1];
  int k = beg + eg;
  for (; k + 8 < end; k += 16) {
    int s0 = csr[k];
    int s1 = csr[k + 8];
    uint4 u0 = *(const uint4*)&hh[(size_t)s0 * COUT + q * 8];
    uint4 u1 = *(const uint4*)&hh[(size_t)s1 * COUT + q * 8];
    acc8(acc, u0);
    acc8(acc2, u1);
  }
  if (k < end) {
    int s0 = csr[k];
    uint4 u0 = *(const uint4*)&hh[(size_t)s0 * COUT + q * 8];
    acc8(acc, u0);
  }
#pragma unroll
  for (int j = 0; j < 8; ++j) acc[j] += acc2[j];
#pragma unroll
  for (int j = 0; j < 8; ++j) {
    acc[j] += __shfl_xor(acc[j], 8);
    acc[j] += __shfl_xor(acc[j], 16);
    acc[j] += __shfl_xor(acc[j], 32);
  }
  if (eg == 0) {
    uint4 u = *(const uint4*)&hh[(size_t)node * COUT + q * 8];  // self-loop
    acc8(acc, u);
    const float dn = dinv[node];
    float4 b0 = *(const float4*)&bias[q * 8];
    float4 b1 = *(const float4*)&bias[q * 8 + 4];
    float4 o0, o1;
    o0.x = dn * acc[0] + b0.x; o0.y = dn * acc[1] + b0.y;
    o0.z = dn * acc[2] + b0.z; o0.w = dn * acc[3] + b0.w;
    o1.x = dn * acc[4] + b1.x; o1.y = dn * acc[5] + b1.y;
    o1.z = dn * acc[6] + b1.z; o1.w = dn * acc[7] + b1.w;
    *(float4*)&out[(size_t)node * COUT + q * 8] = o0;
    *(float4*)&out[(size_t)node * COUT + q * 8 + 4] = o1;
  }
}

extern "C" void kernel_launch(void* const* d_in, const int* in_sizes, int n_in,
                              void* d_out, int out_size, void* d_ws, size_t ws_size,
                              hipStream_t stream) {
  const float* x  = (const float*)d_in[0];
  const int*   ei = (const int*)d_in[1];
  const float* W1 = (const float*)d_in[2];
  const float* b1 = (const float*)d_in[3];
  const float* W2 = (const float*)d_in[4];
  const float* b2 = (const float*)d_in[5];
  float* out = (float*)d_out;

  const int n = in_sizes[0] / CIN;  // 50000
  const int e = in_sizes[1] / 2;    // 800000
  const int* src = ei;
  const int* dst = ei + e;
  const int nbk = (n + 255) >> 8;   // buckets (196)

  // workspace layout (aligned 256B)
  size_t off = 0;
  auto alloc = [&](size_t bytes) {
    size_t o = off;
    off = (off + bytes + 255) & ~(size_t)255;
    return o;
  };
  char* ws = (char*)d_ws;
  int*      cntmat = (int*)(ws + alloc((size_t)NSCAT * 256 * 4));
  int*      btot   = (int*)(ws + alloc(256 * 4));
  int*      rowptr = (int*)(ws + alloc((size_t)(n + 1) * 4));
  float*    dinv   = (float*)(ws + alloc((size_t)n * 4));
  ushort_t* csr    = (ushort_t*)(ws + alloc((size_t)e * 2));
  int*      pairs  = (int*)(ws + alloc((size_t)e * 4));
  ushort_t* wt1    = (ushort_t*)(ws + alloc((size_t)CIN * CHID * 2));
  ushort_t* wt2    = (ushort_t*)(ws + alloc((size_t)CHID * COUT * 2));
  ushort_t* hhA    = (ushort_t*)(ws + alloc((size_t)n * CHID * 2));
  ushort_t* hhB    = (ushort_t*)(ws + alloc((size_t)n * CHID * 2));

  const int WTB = (CIN * CHID + CHID * COUT + 255) / 256;  // 160

  // --- hist + weight transpose (1 dispatch) ---
  k_pre<<<NSCAT + WTB, 256, 0, stream>>>(dst, cntmat, W1, W2, wt1, wt2, e, nbk);
  // --- offsets (parallel) ---
  k_colscan<<<nbk, NSCAT, 0, stream>>>(cntmat, btot, nbk);
  // --- scatter packed pairs ---
  k_bscatter<<<NSCAT, 256, 0, stream>>>(src, dst, cntmat, btot, pairs, e, nbk);
  // --- per-bucket CSR + rowptr + dinv ---
  k_bbuild<<<nbk, 256, 0, stream>>>(pairs, btot, rowptr, dinv, csr, n, e, nbk);

  // --- layer 1 ---
  k_gemm_mfma<CIN, CHID, false><<<(n + 127) / 128, 256, 0, stream>>>(
      x, wt1, dinv, hhA, n);
  k_aggw_h<<<(n + 3) / 4, 256, 0, stream>>>(hhA, rowptr, csr, dinv, b1, hhB, n);

  // --- layer 2 ---
  k_gemm_mfma<CHID, COUT, true><<<(n + 127) / 128, 256, 0, stream>>>(
      hhB, wt2, dinv, hhA, n);
  k_aggw_o<<<(n + 3) / 4, 256, 0, stream>>>(hhA, rowptr, csr, dinv, b2, out, n);
}